// Round 1
// baseline (1685.377 us; speedup 1.0000x reference)
//
#include <hip/hip_runtime.h>
#include <hip/hip_bf16.h>
#include <math.h>

#define VOCAB 50257
#define EMB   1024
#define NROWS 4096

#define BM 128
#define BN 128
#define BK 32
#define NKT (EMB / BK)

typedef __attribute__((ext_vector_type(4))) float  f32x4;
typedef __attribute__((ext_vector_type(4))) __bf16 bf16x4;
typedef __attribute__((ext_vector_type(8))) __bf16 bf16x8;

// Swizzled LDS element index for a [128][32] bf16 tile (row stride 64B).
// 16B slots XOR'd with (row>>1)&3 so that a fragment read (lanes 0..15 on
// consecutive rows, fixed k-slot) lands 2-way-per-bank (free) instead of 8-way.
// Same mapping used on write and read (both-sides-or-neither).
__device__ __forceinline__ int swz_idx(int row, int col) {
    int slot = (col >> 3) ^ ((row >> 1) & 3);
    return row * BK + slot * 8 + (col & 7);
}

__global__ __launch_bounds__(256, 2)
void gemm_logits(const float* __restrict__ H, const float* __restrict__ W,
                 float* __restrict__ C) {
    __shared__ __bf16 ldsA[BM * BK];
    __shared__ __bf16 ldsB[BN * BK];

    const int tid  = threadIdx.x;
    const int lane = tid & 63;
    const int wave = tid >> 6;
    const int wm = (wave >> 1) * 64;   // wave's M offset in tile
    const int wn = (wave & 1) * 64;    // wave's N offset in tile

    const int mt = blockIdx.x;         // m-fastest: W panel reused by 32 blocks
    const int nt = blockIdx.y;

    // staging: thread covers one row-half (16 floats) of the 128x32 tile
    const int srow = tid >> 1;
    const int scol = (tid & 1) * 16;

    const int arow_g = mt * BM + srow;           // always < 4096
    const int brow_g = nt * BN + srow;           // may exceed VOCAB
    const bool bvalid = brow_g < VOCAB;

    const float* aptr = H + (size_t)arow_g * EMB + scol;
    const float* bptr = W + (size_t)(bvalid ? brow_g : 0) * EMB + scol;

    f32x4 areg[4], breg[4];
    #pragma unroll
    for (int q = 0; q < 4; ++q) {
        areg[q] = *(const f32x4*)(aptr + q * 4);
        breg[q] = *(const f32x4*)(bptr + q * 4);
    }

    f32x4 acc[4][4];
    const f32x4 vzero = {0.f, 0.f, 0.f, 0.f};
    #pragma unroll
    for (int i = 0; i < 4; ++i)
        #pragma unroll
        for (int j = 0; j < 4; ++j)
            acc[i][j] = vzero;

    const int frow = lane & 15;
    const int kcol = (lane >> 4) * 8;

    for (int kt = 0; kt < NKT; ++kt) {
        __syncthreads();   // LDS free to overwrite
        #pragma unroll
        for (int q = 0; q < 4; ++q) {
            const int col = scol + q * 4;
            bf16x4 av, bv;
            #pragma unroll
            for (int e = 0; e < 4; ++e) {
                av[e] = (__bf16)areg[q][e];
                bv[e] = bvalid ? (__bf16)breg[q][e] : (__bf16)0.0f;
            }
            *(bf16x4*)(&ldsA[swz_idx(srow, col)]) = av;
            *(bf16x4*)(&ldsB[swz_idx(srow, col)]) = bv;
        }
        __syncthreads();   // tile ready

        // prefetch next K-tile while this tile computes (2-phase pipeline)
        if (kt + 1 < NKT) {
            const int ko = (kt + 1) * BK;
            #pragma unroll
            for (int q = 0; q < 4; ++q) {
                areg[q] = *(const f32x4*)(aptr + ko + q * 4);
                breg[q] = *(const f32x4*)(bptr + ko + q * 4);
            }
        }

        bf16x8 af[4], bfr[4];
        #pragma unroll
        for (int i = 0; i < 4; ++i) {
            af[i]  = *(const bf16x8*)(&ldsA[swz_idx(wm + i * 16 + frow, kcol)]);
            bfr[i] = *(const bf16x8*)(&ldsB[swz_idx(wn + i * 16 + frow, kcol)]);
        }
        #pragma unroll
        for (int i = 0; i < 4; ++i)
            #pragma unroll
            for (int j = 0; j < 4; ++j)
                acc[i][j] = __builtin_amdgcn_mfma_f32_16x16x32_bf16(
                    af[i], bfr[j], acc[i][j], 0, 0, 0);
    }

    // C/D layout: col = lane&15, row = (lane>>4)*4 + reg
    const int crow = mt * BM + wm + (lane >> 4) * 4;
    const int ccol = nt * BN + wn + (lane & 15);
    #pragma unroll
    for (int i = 0; i < 4; ++i) {
        #pragma unroll
        for (int j = 0; j < 4; ++j) {
            const int col = ccol + j * 16;
            if (col < VOCAB) {
                #pragma unroll
                for (int r = 0; r < 4; ++r) {
                    C[(size_t)(crow + i * 16 + r) * VOCAB + col] = acc[i][j][r];
                }
            }
        }
    }
}

// One block per row: online (max, sumexp) -> lse[row]
__global__ __launch_bounds__(256)
void row_lse(const float* __restrict__ C, float* __restrict__ lse) {
    const int row = blockIdx.x;
    const float* p = C + (size_t)row * VOCAB;

    float m = -INFINITY, l = 0.0f;
    for (int c = threadIdx.x; c < VOCAB; c += 256) {
        const float x = p[c];
        const float mn = fmaxf(m, x);
        l = l * __expf(m - mn) + __expf(x - mn);
        m = mn;
    }
    // wave butterfly reduce (64 lanes)
    #pragma unroll
    for (int off = 1; off < 64; off <<= 1) {
        const float mo = __shfl_xor(m, off);
        const float lo = __shfl_xor(l, off);
        const float mn = fmaxf(m, mo);
        l = l * __expf(m - mn) + lo * __expf(mo - mn);
        m = mn;
    }
    __shared__ float sm[4], sl[4];
    if ((threadIdx.x & 63) == 0) { sm[threadIdx.x >> 6] = m; sl[threadIdx.x >> 6] = l; }
    __syncthreads();
    if (threadIdx.x == 0) {
        m = sm[0]; l = sl[0];
        #pragma unroll
        for (int w = 1; w < 4; ++w) {
            const float mn = fmaxf(m, sm[w]);
            l = l * __expf(m - mn) + sl[w] * __expf(sm[w] - mn);
            m = mn;
        }
        lse[row] = m + __logf(l);
    }
}

// out[row][col] -= lse[row]
__global__ __launch_bounds__(256)
void sub_lse(float* __restrict__ C, const float* __restrict__ lse) {
    const int row = blockIdx.y;
    const int c0  = blockIdx.x * 2048;
    const float s = lse[row];
    float* p = C + (size_t)row * VOCAB;
    #pragma unroll
    for (int i = 0; i < 8; ++i) {
        const int c = c0 + i * 256 + threadIdx.x;
        if (c < VOCAB) p[c] -= s;
    }
}

extern "C" void kernel_launch(void* const* d_in, const int* in_sizes, int n_in,
                              void* d_out, int out_size, void* d_ws, size_t ws_size,
                              hipStream_t stream) {
    const float* H = (const float*)d_in[0];   // [4096][1024]
    const float* W = (const float*)d_in[1];   // [50257][1024]
    float* C   = (float*)d_out;               // [4096][50257]
    float* lse = (float*)d_ws;                // 4096 floats

    dim3 ggrid(NROWS / BM, (VOCAB + BN - 1) / BN);   // (32, 393), m-fastest
    gemm_logits<<<ggrid, 256, 0, stream>>>(H, W, C);

    row_lse<<<dim3(NROWS), 256, 0, stream>>>(C, lse);

    dim3 sgrid((VOCAB + 2047) / 2048, NROWS);        // (25, 4096)
    sub_lse<<<sgrid, 256, 0, stream>>>(C, lse);
}

// Round 2
// 1322.553 us; speedup vs baseline: 1.2743x; 1.2743x over previous
//
#include <hip/hip_runtime.h>
#include <hip/hip_bf16.h>
#include <math.h>

#define VOCAB 50257
#define VPAD  50304          // VOCAB padded to multiple of 128
#define EMB   1024
#define NROWS 4096

#define BM 128
#define BN 128
#define GBK 64
#define GNKT (EMB / GBK)     // 16

typedef __attribute__((ext_vector_type(4))) float  f32x4;
typedef __attribute__((ext_vector_type(4), aligned(4))) float f32x4u;
typedef __attribute__((ext_vector_type(4))) __bf16 bf16x4;
typedef __attribute__((ext_vector_type(8))) __bf16 bf16x8;

// ---------------------------------------------------------------------------
// fp32 -> bf16 convert (pads tail with zeros). n_src, n_dst multiples of 8.
// ---------------------------------------------------------------------------
__global__ __launch_bounds__(256)
void cvt_bf16(const float* __restrict__ src, __bf16* __restrict__ dst,
              long n_src, long n_dst) {
    long i = ((long)blockIdx.x * 256 + threadIdx.x) * 8;
    if (i >= n_dst) return;
    bf16x8 o;
    if (i < n_src) {
        f32x4 a = *(const f32x4*)(src + i);
        f32x4 b = *(const f32x4*)(src + i + 4);
        #pragma unroll
        for (int e = 0; e < 4; ++e) {
            o[e]     = (__bf16)a[e];
            o[4 + e] = (__bf16)b[e];
        }
    } else {
        #pragma unroll
        for (int e = 0; e < 8; ++e) o[e] = (__bf16)0.0f;
    }
    *(bf16x8*)(dst + i) = o;
}

// ---------------------------------------------------------------------------
// bf16 GEMM: C[4096][50257] (fp32) = Hb[4096][1024] @ Wb[50304][1024]^T
// 128x128 tile, BK=64, 4 waves (2x2 of 64x64), global_load_lds(16B) staging,
// double-buffered LDS, one raw barrier + vmcnt(0) per K-step (T3 2-phase).
// LDS read swizzle slot^=(row&7); global source pre-swizzled identically.
// ---------------------------------------------------------------------------
__global__ __launch_bounds__(256, 2)
void gemm_bf16(const __bf16* __restrict__ A, const __bf16* __restrict__ B,
               float* __restrict__ C) {
    __shared__ __bf16 lds[2][2][BM * GBK];   // [dbuf][A/B][8192] = 64 KB

    const int tid  = threadIdx.x;
    const int lane = tid & 63;
    const int wave = tid >> 6;
    const int wm = (wave >> 1) * 64;
    const int wn = (wave & 1) * 64;

    // bijective XCD swizzle: nwg = 32*393 = 12576, 12576 % 8 == 0, q = 1572
    const int b   = blockIdx.x;
    const int lg  = (b & 7) * 1572 + (b >> 3);
    const int mt  = lg & 31;          // m-fastest: 32 blocks share one W panel
    const int nt  = lg >> 5;

    const __bf16* Abase = A + (size_t)(mt * BM) * EMB;
    const __bf16* Bbase = B + (size_t)(nt * BN) * EMB;

    // staging: wave w covers slot-groups [w*4, w*4+4); each group = 64 slots
    // of 16B = 8 rows. Lane l -> slot n = g*64+l -> row n>>3, slot n&7.
    const int n0 = wave * 4;

    // fragment indices
    const int frow = lane & 15;
    const int hi   = lane >> 4;

    f32x4 acc[4][4];
    const f32x4 vzero = {0.f, 0.f, 0.f, 0.f};
    #pragma unroll
    for (int i = 0; i < 4; ++i)
        #pragma unroll
        for (int j = 0; j < 4; ++j) acc[i][j] = vzero;

#define STAGE(BUF, KT)                                                        \
    {                                                                         \
        _Pragma("unroll")                                                     \
        for (int j = 0; j < 4; ++j) {                                         \
            const int n   = (n0 + j) * 64 + lane;                             \
            const int row = n >> 3;                                           \
            const int ls  = (n & 7) ^ (row & 7);                              \
            const __bf16* ga = Abase + (size_t)row * EMB + (KT) * GBK + ls * 8; \
            const __bf16* gb = Bbase + (size_t)row * EMB + (KT) * GBK + ls * 8; \
            __builtin_amdgcn_global_load_lds(                                 \
                (const __attribute__((address_space(1))) void*)ga,           \
                (__attribute__((address_space(3))) void*)&lds[BUF][0][(n0 + j) * 512], \
                16, 0, 0);                                                    \
            __builtin_amdgcn_global_load_lds(                                 \
                (const __attribute__((address_space(1))) void*)gb,           \
                (__attribute__((address_space(3))) void*)&lds[BUF][1][(n0 + j) * 512], \
                16, 0, 0);                                                    \
        }                                                                     \
    }

    STAGE(0, 0);
    asm volatile("s_waitcnt vmcnt(0)" ::: "memory");
    __builtin_amdgcn_s_barrier();

    int cur = 0;
    for (int kt = 0; kt < GNKT; ++kt) {
        if (kt + 1 < GNKT) STAGE(cur ^ 1, kt + 1);   // loads fly over MFMAs

        #pragma unroll
        for (int ks = 0; ks < 2; ++ks) {
            bf16x8 af[4], bfr[4];
            #pragma unroll
            for (int i = 0; i < 4; ++i) {
                const int ra = wm + i * 16 + frow;
                const int rb = wn + i * 16 + frow;
                af[i]  = *(const bf16x8*)&lds[cur][0][ra * GBK + ((((ks << 2) | hi)) ^ (ra & 7)) * 8];
                bfr[i] = *(const bf16x8*)&lds[cur][1][rb * GBK + ((((ks << 2) | hi)) ^ (rb & 7)) * 8];
            }
            __builtin_amdgcn_s_setprio(1);
            #pragma unroll
            for (int i = 0; i < 4; ++i)
                #pragma unroll
                for (int j = 0; j < 4; ++j)
                    acc[i][j] = __builtin_amdgcn_mfma_f32_16x16x32_bf16(
                        af[i], bfr[j], acc[i][j], 0, 0, 0);
            __builtin_amdgcn_s_setprio(0);
        }
        asm volatile("s_waitcnt vmcnt(0)" ::: "memory");   // next tile staged
        __builtin_amdgcn_s_barrier();                      // all waves see it
        cur ^= 1;
    }
#undef STAGE

    // C/D layout: col = lane&15, row = (lane>>4)*4 + reg
    const int crow = mt * BM + wm + hi * 4;
    const int ccol = nt * BN + wn + frow;
    #pragma unroll
    for (int i = 0; i < 4; ++i) {
        #pragma unroll
        for (int j = 0; j < 4; ++j) {
            const int col = ccol + j * 16;
            if (col < VOCAB) {
                #pragma unroll
                for (int r = 0; r < 4; ++r)
                    C[(size_t)(crow + i * 16 + r) * VOCAB + col] = acc[i][j][r];
            }
        }
    }
}

// ---------------------------------------------------------------------------
// fallback fp32-input GEMM (round-1 kernel) if ws too small for bf16 copies
// ---------------------------------------------------------------------------
#define FBK 32
__device__ __forceinline__ int swz_idx(int row, int col) {
    int slot = (col >> 3) ^ ((row >> 1) & 3);
    return row * FBK + slot * 8 + (col & 7);
}

__global__ __launch_bounds__(256, 2)
void gemm_logits(const float* __restrict__ H, const float* __restrict__ W,
                 float* __restrict__ C) {
    __shared__ __bf16 ldsA[BM * FBK];
    __shared__ __bf16 ldsB[BN * FBK];

    const int tid  = threadIdx.x;
    const int lane = tid & 63;
    const int wave = tid >> 6;
    const int wm = (wave >> 1) * 64;
    const int wn = (wave & 1) * 64;
    const int mt = blockIdx.x;
    const int nt = blockIdx.y;
    const int srow = tid >> 1;
    const int scol = (tid & 1) * 16;
    const int arow_g = mt * BM + srow;
    const int brow_g = nt * BN + srow;
    const bool bvalid = brow_g < VOCAB;
    const float* aptr = H + (size_t)arow_g * EMB + scol;
    const float* bptr = W + (size_t)(bvalid ? brow_g : 0) * EMB + scol;

    f32x4 areg[4], breg[4];
    #pragma unroll
    for (int q = 0; q < 4; ++q) {
        areg[q] = *(const f32x4*)(aptr + q * 4);
        breg[q] = *(const f32x4*)(bptr + q * 4);
    }
    f32x4 acc[4][4];
    const f32x4 vzero = {0.f, 0.f, 0.f, 0.f};
    #pragma unroll
    for (int i = 0; i < 4; ++i)
        #pragma unroll
        for (int j = 0; j < 4; ++j) acc[i][j] = vzero;

    const int frow = lane & 15;
    const int kcol = (lane >> 4) * 8;

    for (int kt = 0; kt < EMB / FBK; ++kt) {
        __syncthreads();
        #pragma unroll
        for (int q = 0; q < 4; ++q) {
            const int col = scol + q * 4;
            bf16x4 av, bv;
            #pragma unroll
            for (int e = 0; e < 4; ++e) {
                av[e] = (__bf16)areg[q][e];
                bv[e] = bvalid ? (__bf16)breg[q][e] : (__bf16)0.0f;
            }
            *(bf16x4*)(&ldsA[swz_idx(srow, col)]) = av;
            *(bf16x4*)(&ldsB[swz_idx(srow, col)]) = bv;
        }
        __syncthreads();
        if (kt + 1 < EMB / FBK) {
            const int ko = (kt + 1) * FBK;
            #pragma unroll
            for (int q = 0; q < 4; ++q) {
                areg[q] = *(const f32x4*)(aptr + ko + q * 4);
                breg[q] = *(const f32x4*)(bptr + ko + q * 4);
            }
        }
        bf16x8 af[4], bfr[4];
        #pragma unroll
        for (int i = 0; i < 4; ++i) {
            af[i]  = *(const bf16x8*)(&ldsA[swz_idx(wm + i * 16 + frow, kcol)]);
            bfr[i] = *(const bf16x8*)(&ldsB[swz_idx(wn + i * 16 + frow, kcol)]);
        }
        #pragma unroll
        for (int i = 0; i < 4; ++i)
            #pragma unroll
            for (int j = 0; j < 4; ++j)
                acc[i][j] = __builtin_amdgcn_mfma_f32_16x16x32_bf16(
                    af[i], bfr[j], acc[i][j], 0, 0, 0);
    }

    const int crow = mt * BM + wm + (lane >> 4) * 4;
    const int ccol = nt * BN + wn + (lane & 15);
    #pragma unroll
    for (int i = 0; i < 4; ++i) {
        #pragma unroll
        for (int j = 0; j < 4; ++j) {
            const int col = ccol + j * 16;
            if (col < VOCAB) {
                #pragma unroll
                for (int r = 0; r < 4; ++r)
                    C[(size_t)(crow + i * 16 + r) * VOCAB + col] = acc[i][j][r];
            }
        }
    }
}

// ---------------------------------------------------------------------------
// One block per row: online (max, sumexp) -> lse[row]. 50257 = 12564*4 + 1.
// ---------------------------------------------------------------------------
__global__ __launch_bounds__(256)
void row_lse(const float* __restrict__ C, float* __restrict__ lse) {
    const int row = blockIdx.x;
    const float* p = C + (size_t)row * VOCAB;

    float m = -INFINITY, l = 0.0f;
    for (int i = threadIdx.x; i < 12564; i += 256) {
        f32x4u v = *(const f32x4u*)(p + 4 * i);
        #pragma unroll
        for (int e = 0; e < 4; ++e) {
            const float x  = v[e];
            const float mn = fmaxf(m, x);
            l = l * __expf(m - mn) + __expf(x - mn);
            m = mn;
        }
    }
    if (threadIdx.x == 0) {   // tail element 50256
        const float x  = p[50256];
        const float mn = fmaxf(m, x);
        l = l * __expf(m - mn) + __expf(x - mn);
        m = mn;
    }
    #pragma unroll
    for (int off = 1; off < 64; off <<= 1) {
        const float mo = __shfl_xor(m, off);
        const float lo = __shfl_xor(l, off);
        const float mn = fmaxf(m, mo);
        l = l * __expf(m - mn) + lo * __expf(mo - mn);
        m = mn;
    }
    __shared__ float sm[4], sl[4];
    if ((threadIdx.x & 63) == 0) { sm[threadIdx.x >> 6] = m; sl[threadIdx.x >> 6] = l; }
    __syncthreads();
    if (threadIdx.x == 0) {
        m = sm[0]; l = sl[0];
        #pragma unroll
        for (int w = 1; w < 4; ++w) {
            const float mn = fmaxf(m, sm[w]);
            l = l * __expf(m - mn) + sl[w] * __expf(sm[w] - mn);
            m = mn;
        }
        lse[row] = m + __logf(l);
    }
}

// ---------------------------------------------------------------------------
// out[row][col] -= lse[row], vectorized f32x4 (dword-aligned is enough)
// ---------------------------------------------------------------------------
__global__ __launch_bounds__(256)
void sub_lse(float* __restrict__ C, const float* __restrict__ lse) {
    const int row = blockIdx.y;
    const float s = lse[row];
    float* p = C + (size_t)row * VOCAB;
    const int i = blockIdx.x * 256 + threadIdx.x;   // chunk of 4
    const int c = i * 4;
    if (c + 3 < VOCAB) {
        f32x4u v = *(const f32x4u*)(p + c);
        v[0] -= s; v[1] -= s; v[2] -= s; v[3] -= s;
        *(f32x4u*)(p + c) = v;
    } else if (c < VOCAB) {
        for (int e = 0; e < VOCAB - c; ++e) p[c + e] -= s;
    }
}

// ---------------------------------------------------------------------------
extern "C" void kernel_launch(void* const* d_in, const int* in_sizes, int n_in,
                              void* d_out, int out_size, void* d_ws, size_t ws_size,
                              hipStream_t stream) {
    const float* H = (const float*)d_in[0];   // [4096][1024]
    const float* W = (const float*)d_in[1];   // [50257][1024]
    float* C   = (float*)d_out;               // [4096][50257]
    float* lse = (float*)d_ws;                // 4096 floats

    const size_t hb_off = 16384;
    const size_t wb_off = hb_off + (size_t)NROWS * EMB * 2;           // 8 MB later
    const size_t need   = wb_off + (size_t)VPAD * EMB * 2;            // ~106 MiB

    if (ws_size >= need) {
        __bf16* Hb = (__bf16*)((char*)d_ws + hb_off);
        __bf16* Wb = (__bf16*)((char*)d_ws + wb_off);

        const long nH = (long)NROWS * EMB;                  // 4,194,304
        const long nW = (long)VOCAB * EMB;                  // 51,463,168
        const long nWp = (long)VPAD * EMB;                  // 51,511,296
        cvt_bf16<<<(int)(nH / 8 / 256), 256, 0, stream>>>(H, Hb, nH, nH);
        cvt_bf16<<<(int)((nWp / 8 + 255) / 256), 256, 0, stream>>>(W, Wb, nW, nWp);

        gemm_bf16<<<dim3(32 * (VPAD / BN)), 256, 0, stream>>>(Hb, Wb, C);
    } else {
        dim3 ggrid(NROWS / BM, (VOCAB + BN - 1) / BN);
        gemm_logits<<<ggrid, 256, 0, stream>>>(H, W, C);
    }

    row_lse<<<dim3(NROWS), 256, 0, stream>>>(C, lse);

    dim3 sgrid((VOCAB / 4 + 255) / 256, NROWS);   // (50, 4096)
    sub_lse<<<sgrid, 256, 0, stream>>>(C, lse);
}